// Round 4
// baseline (231.960 us; speedup 1.0000x reference)
//
#include <hip/hip_runtime.h>
#include <hip/hip_bf16.h>

#define E_EDGES 1000000
#define N_NODES 100000
#define HDIM 128
#define BM 64
#define LDP 136   // padded LDS row stride for bf16 tiles
#define LDS_F 132 // padded LDS row stride for f32 S tile

typedef __attribute__((ext_vector_type(8))) short short8;
typedef __attribute__((ext_vector_type(4))) float f32x4;

// f32 -> bf16 round-to-nearest-even (bit trick, validated)
static __device__ __forceinline__ short f2bf(float f) {
  unsigned int u = __float_as_uint(f);
  unsigned int r = (u + 0x7FFFu + ((u >> 16) & 1u)) >> 16;
  return (short)r;
}
static __device__ __forceinline__ float bf2f(short s) {
  return __uint_as_float(((unsigned int)(unsigned short)s) << 16);
}
// packed f32x2 -> bf16x2 RNE via compiler-visible intrinsic (can emit v_cvt_pk_bf16_f32)
static __device__ __forceinline__ unsigned int pack_bf16_rn(float lo, float hi) {
  __hip_bfloat162 h = __float22bfloat162_rn(make_float2(lo, hi));
  unsigned int u;
  __builtin_memcpy(&u, &h, 4);
  return u;
}

// ---- k0: transpose + bf16-ize weights: Wt[out][in] row-major ----
__global__ void prep_weights(const float* __restrict__ Wp, const float* __restrict__ Wc,
                             const float* __restrict__ W1, const float* __restrict__ W2,
                             short* __restrict__ wp_t, short* __restrict__ wc_t,
                             short* __restrict__ w1_t, float* __restrict__ w2v) {
  int i = blockIdx.x * 256 + threadIdx.x;
  if (i < HDIM * HDIM) {
    int o = i >> 7, k = i & (HDIM - 1);
    wp_t[i] = f2bf(Wp[k * HDIM + o]);
    wc_t[i] = f2bf(Wc[k * HDIM + o]);
  }
  if (i < HDIM * 3 * HDIM) {
    int o = i / (3 * HDIM), k = i - o * (3 * HDIM);
    w1_t[i] = f2bf(W1[k * HDIM + o]);
  }
  if (i < HDIM) w2v[i] = W2[i];
}

// ---- k1: per-node precompute ----
// x_bf[n] = bf16(x[n]);  A[n] = bf16(lrelu(x@Wp+bp)@W1a + b1);  B[n] = bf16(lrelu(x@Wc+bc)@W1b)
__global__ __launch_bounds__(256) void node_precompute(
    const float* __restrict__ x, const float* __restrict__ b_p,
    const float* __restrict__ b_c, const float* __restrict__ b1,
    const short* __restrict__ wp_t, const short* __restrict__ wc_t,
    const short* __restrict__ w1_t,
    short* __restrict__ x_bf, short* __restrict__ Abuf, short* __restrict__ Bbuf) {
  __shared__ __align__(16) short Xt[BM * LDP];
  __shared__ __align__(16) short Yp[BM * LDP];
  __shared__ __align__(16) short Yc[BM * LDP];

  const int t = threadIdx.x;
  const int n0 = blockIdx.x * BM;

  {
    const int lane16 = t & 15, rq = t >> 4, c0 = lane16 * 8;
#pragma unroll
    for (int pass = 0; pass < 4; ++pass) {
      const int row = pass * 16 + rq;
      const int n = n0 + row;
      short8 v;
      if (n < N_NODES) {
        const float* ps = x + (size_t)n * HDIM + c0;
        float4 a = *(const float4*)ps;
        float4 b = *(const float4*)(ps + 4);
        float f[8] = {a.x, a.y, a.z, a.w, b.x, b.y, b.z, b.w};
#pragma unroll
        for (int j = 0; j < 8; ++j) v[j] = f2bf(f[j]);
        *(short8*)&x_bf[(size_t)n * HDIM + c0] = v;
      } else {
#pragma unroll
        for (int j = 0; j < 8; ++j) v[j] = 0;
      }
      *(short8*)&Xt[row * LDP + c0] = v;
    }
  }
  __syncthreads();

  const int l = t & 63;
  const int w = t >> 6;
  const int lr = l & 15;
  const int lg = l >> 4;
  const int aoff = lr * LDP + lg * 8;
  const int na = w * 32 + lr, nb = na + 16;

  const f32x4 zero4 = {0.f, 0.f, 0.f, 0.f};
  f32x4 ap_[4][2], ac_[4][2];
#pragma unroll
  for (int mi = 0; mi < 4; ++mi) {
    ap_[mi][0] = zero4; ap_[mi][1] = zero4;
    ac_[mi][0] = zero4; ac_[mi][1] = zero4;
  }

  const short* wpA = wp_t + na * HDIM + lg * 8;
  const short* wpB = wp_t + nb * HDIM + lg * 8;
  const short* wcA = wc_t + na * HDIM + lg * 8;
  const short* wcB = wc_t + nb * HDIM + lg * 8;

#pragma unroll
  for (int kk = 0; kk < 4; ++kk) {
    short8 b10 = *(const short8*)(wpA + kk * 32);
    short8 b11 = *(const short8*)(wpB + kk * 32);
    short8 b20 = *(const short8*)(wcA + kk * 32);
    short8 b21 = *(const short8*)(wcB + kk * 32);
#pragma unroll
    for (int mi = 0; mi < 4; ++mi) {
      short8 a8 = *(const short8*)&Xt[mi * 16 * LDP + aoff + kk * 32];
      ap_[mi][0] = __builtin_amdgcn_mfma_f32_16x16x32_bf16(a8, b10, ap_[mi][0], 0, 0, 0);
      ap_[mi][1] = __builtin_amdgcn_mfma_f32_16x16x32_bf16(a8, b11, ap_[mi][1], 0, 0, 0);
      ac_[mi][0] = __builtin_amdgcn_mfma_f32_16x16x32_bf16(a8, b20, ac_[mi][0], 0, 0, 0);
      ac_[mi][1] = __builtin_amdgcn_mfma_f32_16x16x32_bf16(a8, b21, ac_[mi][1], 0, 0, 0);
    }
  }

  {
    const float bpa = b_p[na], bpb = b_p[nb];
    const float bca = b_c[na], bcb = b_c[nb];
#pragma unroll
    for (int mi = 0; mi < 4; ++mi) {
#pragma unroll
      for (int r = 0; r < 4; ++r) {
        const int m = mi * 16 + lg * 4 + r;
        float v0 = ap_[mi][0][r] + bpa; v0 = v0 > 0.f ? v0 : 0.01f * v0;
        float v1 = ap_[mi][1][r] + bpb; v1 = v1 > 0.f ? v1 : 0.01f * v1;
        float u0 = ac_[mi][0][r] + bca; u0 = u0 > 0.f ? u0 : 0.01f * u0;
        float u1 = ac_[mi][1][r] + bcb; u1 = u1 > 0.f ? u1 : 0.01f * u1;
        Yp[m * LDP + na] = f2bf(v0);
        Yp[m * LDP + nb] = f2bf(v1);
        Yc[m * LDP + na] = f2bf(u0);
        Yc[m * LDP + nb] = f2bf(u1);
      }
    }
  }
  __syncthreads();

  f32x4 aa_[4][2], ab_[4][2];
#pragma unroll
  for (int mi = 0; mi < 4; ++mi) {
    aa_[mi][0] = zero4; aa_[mi][1] = zero4;
    ab_[mi][0] = zero4; ab_[mi][1] = zero4;
  }
  const short* w1Aa = w1_t + na * (3 * HDIM) + lg * 8;
  const short* w1Ab = w1_t + nb * (3 * HDIM) + lg * 8;
#pragma unroll
  for (int kk = 0; kk < 4; ++kk) {
    short8 ba0 = *(const short8*)(w1Aa + kk * 32);
    short8 ba1 = *(const short8*)(w1Ab + kk * 32);
    short8 bb0 = *(const short8*)(w1Aa + HDIM + kk * 32);
    short8 bb1 = *(const short8*)(w1Ab + HDIM + kk * 32);
#pragma unroll
    for (int mi = 0; mi < 4; ++mi) {
      short8 ayp = *(const short8*)&Yp[mi * 16 * LDP + aoff + kk * 32];
      short8 ayc = *(const short8*)&Yc[mi * 16 * LDP + aoff + kk * 32];
      aa_[mi][0] = __builtin_amdgcn_mfma_f32_16x16x32_bf16(ayp, ba0, aa_[mi][0], 0, 0, 0);
      aa_[mi][1] = __builtin_amdgcn_mfma_f32_16x16x32_bf16(ayp, ba1, aa_[mi][1], 0, 0, 0);
      ab_[mi][0] = __builtin_amdgcn_mfma_f32_16x16x32_bf16(ayc, bb0, ab_[mi][0], 0, 0, 0);
      ab_[mi][1] = __builtin_amdgcn_mfma_f32_16x16x32_bf16(ayc, bb1, ab_[mi][1], 0, 0, 0);
    }
  }

  {
    const float b1a = b1[na], b1b = b1[nb];
#pragma unroll
    for (int mi = 0; mi < 4; ++mi) {
#pragma unroll
      for (int r = 0; r < 4; ++r) {
        const int m = mi * 16 + lg * 4 + r;
        const int n = n0 + m;
        if (n < N_NODES) {
          Abuf[(size_t)n * HDIM + na] = f2bf(aa_[mi][0][r] + b1a);
          Abuf[(size_t)n * HDIM + nb] = f2bf(aa_[mi][1][r] + b1b);
          Bbuf[(size_t)n * HDIM + na] = f2bf(ab_[mi][0][r]);
          Bbuf[(size_t)n * HDIM + nb] = f2bf(ab_[mi][1][r]);
        }
      }
    }
  }
}

// ---- k2: per-edge: h = relu(S + |x_s-x_d|@W1c); out = sigmoid(h.w2 + b2) ----
// S = A[s] + B[d] staged vectorized into f32 LDS (no scalar global gathers).
__global__ __launch_bounds__(512, 4) void edge_kernel(
    const int* __restrict__ ei, const short* __restrict__ x_bf,
    const short* __restrict__ Abuf, const short* __restrict__ Bbuf,
    const short* __restrict__ w1_t, const float* __restrict__ w2v,
    const float* __restrict__ b2, float* __restrict__ out) {
  __shared__ __align__(16) short Dt[BM * LDP];     // 17408 B
  __shared__ __align__(16) float St[BM * LDS_F];   // 33792 B
  __shared__ float partial[8][BM];                 // 2048 B

  const int t = threadIdx.x;
  const int e0 = blockIdx.x * BM;

  {
    const int lane16 = t & 15, rq = t >> 4, c0 = lane16 * 8;
#pragma unroll
    for (int pass = 0; pass < 2; ++pass) {
      const int row = pass * 32 + rq;
      const int s = ei[e0 + row];
      const int d = ei[E_EDGES + e0 + row];
      short8 p8 = *(const short8*)(x_bf + (size_t)s * HDIM + c0);
      short8 c8 = *(const short8*)(x_bf + (size_t)d * HDIM + c0);
      short8 a8 = *(const short8*)(Abuf + (size_t)s * HDIM + c0);
      short8 b8 = *(const short8*)(Bbuf + (size_t)d * HDIM + c0);
      float df[8];
      float4 s0, s1;
#pragma unroll
      for (int j = 0; j < 8; ++j) df[j] = fabsf(bf2f(p8[j]) - bf2f(c8[j]));
      s0.x = bf2f(a8[0]) + bf2f(b8[0]);
      s0.y = bf2f(a8[1]) + bf2f(b8[1]);
      s0.z = bf2f(a8[2]) + bf2f(b8[2]);
      s0.w = bf2f(a8[3]) + bf2f(b8[3]);
      s1.x = bf2f(a8[4]) + bf2f(b8[4]);
      s1.y = bf2f(a8[5]) + bf2f(b8[5]);
      s1.z = bf2f(a8[6]) + bf2f(b8[6]);
      s1.w = bf2f(a8[7]) + bf2f(b8[7]);
      uint4 vd;
      vd.x = pack_bf16_rn(df[0], df[1]);
      vd.y = pack_bf16_rn(df[2], df[3]);
      vd.z = pack_bf16_rn(df[4], df[5]);
      vd.w = pack_bf16_rn(df[6], df[7]);
      *(uint4*)&Dt[row * LDP + c0] = vd;
      *(float4*)&St[row * LDS_F + c0] = s0;
      *(float4*)&St[row * LDS_F + c0 + 4] = s1;
    }
  }
  __syncthreads();

  const int l = t & 63;
  const int w = t >> 6;   // 0..7
  const int lr = l & 15;
  const int lg = l >> 4;
  const int na = w * 16 + lr;
  const int aoff = lr * LDP + lg * 8;

  // acc init = S (from LDS, 2-way-max bank alias)
  f32x4 acc[4];
#pragma unroll
  for (int mi = 0; mi < 4; ++mi) {
#pragma unroll
    for (int r = 0; r < 4; ++r) {
      acc[mi][r] = St[(mi * 16 + lg * 4 + r) * LDS_F + na];
    }
  }

  // GEMM: D @ W1c (K=128)
  const short* w1D = w1_t + na * (3 * HDIM) + 2 * HDIM + lg * 8;
#pragma unroll
  for (int kk = 0; kk < 4; ++kk) {
    short8 b8 = *(const short8*)(w1D + kk * 32);
#pragma unroll
    for (int mi = 0; mi < 4; ++mi) {
      short8 a8 = *(const short8*)&Dt[mi * 16 * LDP + aoff + kk * 32];
      acc[mi] = __builtin_amdgcn_mfma_f32_16x16x32_bf16(a8, b8, acc[mi], 0, 0, 0);
    }
  }

  // epilogue: relu, dot w2, 16-lane reduce
  {
    const float w2a = w2v[na];
#pragma unroll
    for (int mi = 0; mi < 4; ++mi) {
#pragma unroll
      for (int r = 0; r < 4; ++r) {
        float h = acc[mi][r] > 0.f ? acc[mi][r] : 0.f;
        float v = h * w2a;
        v += __shfl_xor(v, 1);
        v += __shfl_xor(v, 2);
        v += __shfl_xor(v, 4);
        v += __shfl_xor(v, 8);
        if (lr == 0) partial[w][mi * 16 + lg * 4 + r] = v;
      }
    }
  }
  __syncthreads();

  if (t < BM) {
    float z = partial[0][t] + partial[1][t] + partial[2][t] + partial[3][t] +
              partial[4][t] + partial[5][t] + partial[6][t] + partial[7][t] + b2[0];
    out[e0 + t] = 1.0f / (1.0f + __expf(-z));
  }
}

// ---- fallback (validated v2 path) if workspace is too small ----
__global__ __launch_bounds__(512, 4) void edge_weight_fallback(
    const float* __restrict__ x, const int* __restrict__ ei,
    const float* __restrict__ b_p, const float* __restrict__ b_c,
    const float* __restrict__ b1, const float* __restrict__ b2,
    const short* __restrict__ wp_t, const short* __restrict__ wc_t,
    const short* __restrict__ w1_t, const float* __restrict__ w2v,
    float* __restrict__ out) {
  __shared__ __align__(16) short Pt[BM * LDP];
  __shared__ __align__(16) short Ct[BM * LDP];
  __shared__ __align__(16) short Dt[BM * LDP];
  __shared__ float partial[8][BM];

  const int t = threadIdx.x;
  const int e0 = blockIdx.x * BM;
  {
    const int lane16 = t & 15, rq = t >> 4, c0 = lane16 * 8;
#pragma unroll
    for (int pass = 0; pass < 2; ++pass) {
      const int row = pass * 32 + rq;
      const int ip = ei[e0 + row];
      const int ic = ei[E_EDGES + e0 + row];
      const float* ps = x + (size_t)ip * HDIM + c0;
      const float* cs = x + (size_t)ic * HDIM + c0;
      float4 pa = *(const float4*)ps, pb = *(const float4*)(ps + 4);
      float4 ca = *(const float4*)cs, cb = *(const float4*)(cs + 4);
      float pf[8] = {pa.x, pa.y, pa.z, pa.w, pb.x, pb.y, pb.z, pb.w};
      float cf[8] = {ca.x, ca.y, ca.z, ca.w, cb.x, cb.y, cb.z, cb.w};
      short8 vp, vc, vd;
#pragma unroll
      for (int j = 0; j < 8; ++j) {
        vp[j] = f2bf(pf[j]); vc[j] = f2bf(cf[j]); vd[j] = f2bf(fabsf(pf[j] - cf[j]));
      }
      *(short8*)&Pt[row * LDP + c0] = vp;
      *(short8*)&Ct[row * LDP + c0] = vc;
      *(short8*)&Dt[row * LDP + c0] = vd;
    }
  }
  __syncthreads();
  const int l = t & 63, w = t >> 6, lr = l & 15, lg = l >> 4;
  const int n0 = w * 16, na = n0 + lr, aoff = lr * LDP + lg * 8;
  const f32x4 zero4 = {0.f, 0.f, 0.f, 0.f};
  f32x4 acc1[4], acc2[4], acc3[4];
#pragma unroll
  for (int mi = 0; mi < 4; ++mi) { acc1[mi] = zero4; acc2[mi] = zero4; acc3[mi] = zero4; }
  const short* wpA = wp_t + na * HDIM + lg * 8;
  const short* wcA = wc_t + na * HDIM + lg * 8;
  const short* w1A = w1_t + na * (3 * HDIM) + lg * 8;
#pragma unroll
  for (int kk = 0; kk < 4; ++kk) {
    short8 bp8 = *(const short8*)(wpA + kk * 32);
    short8 bc8 = *(const short8*)(wcA + kk * 32);
    short8 bd8 = *(const short8*)(w1A + 2 * HDIM + kk * 32);
#pragma unroll
    for (int mi = 0; mi < 4; ++mi) {
      short8 ap = *(const short8*)&Pt[mi * 16 * LDP + aoff + kk * 32];
      short8 ac = *(const short8*)&Ct[mi * 16 * LDP + aoff + kk * 32];
      short8 ad = *(const short8*)&Dt[mi * 16 * LDP + aoff + kk * 32];
      acc1[mi] = __builtin_amdgcn_mfma_f32_16x16x32_bf16(ap, bp8, acc1[mi], 0, 0, 0);
      acc2[mi] = __builtin_amdgcn_mfma_f32_16x16x32_bf16(ac, bc8, acc2[mi], 0, 0, 0);
      acc3[mi] = __builtin_amdgcn_mfma_f32_16x16x32_bf16(ad, bd8, acc3[mi], 0, 0, 0);
    }
  }
  __syncthreads();
  {
    const float bpa = b_p[na], bca = b_c[na];
#pragma unroll
    for (int mi = 0; mi < 4; ++mi) {
#pragma unroll
      for (int r = 0; r < 4; ++r) {
        const int m = mi * 16 + lg * 4 + r;
        float v0 = acc1[mi][r] + bpa; v0 = v0 > 0.f ? v0 : 0.01f * v0;
        float u0 = acc2[mi][r] + bca; u0 = u0 > 0.f ? u0 : 0.01f * u0;
        Pt[m * LDP + na] = f2bf(v0);
        Ct[m * LDP + na] = f2bf(u0);
      }
    }
  }
  __syncthreads();
#pragma unroll
  for (int kk = 0; kk < 4; ++kk) {
    short8 b0 = *(const short8*)(w1A + kk * 32);
    short8 b1f = *(const short8*)(w1A + HDIM + kk * 32);
#pragma unroll
    for (int mi = 0; mi < 4; ++mi) {
      short8 a0 = *(const short8*)&Pt[mi * 16 * LDP + aoff + kk * 32];
      short8 a1 = *(const short8*)&Ct[mi * 16 * LDP + aoff + kk * 32];
      acc3[mi] = __builtin_amdgcn_mfma_f32_16x16x32_bf16(a0, b0, acc3[mi], 0, 0, 0);
      acc3[mi] = __builtin_amdgcn_mfma_f32_16x16x32_bf16(a1, b1f, acc3[mi], 0, 0, 0);
    }
  }
  {
    const float b1a = b1[na], w2a = w2v[na];
#pragma unroll
    for (int mi = 0; mi < 4; ++mi) {
#pragma unroll
      for (int r = 0; r < 4; ++r) {
        float h0 = acc3[mi][r] + b1a; h0 = h0 > 0.f ? h0 : 0.f;
        float v = h0 * w2a;
        v += __shfl_xor(v, 1); v += __shfl_xor(v, 2);
        v += __shfl_xor(v, 4); v += __shfl_xor(v, 8);
        if (lr == 0) partial[w][mi * 16 + lg * 4 + r] = v;
      }
    }
  }
  __syncthreads();
  if (t < BM) {
    float z = partial[0][t] + partial[1][t] + partial[2][t] + partial[3][t] +
              partial[4][t] + partial[5][t] + partial[6][t] + partial[7][t] + b2[0];
    out[e0 + t] = 1.0f / (1.0f + __expf(-z));
  }
}

extern "C" void kernel_launch(void* const* d_in, const int* in_sizes, int n_in,
                              void* d_out, int out_size, void* d_ws, size_t ws_size,
                              hipStream_t stream) {
  const float* x  = (const float*)d_in[0];
  const int*   ei = (const int*)d_in[1];
  const float* Wp = (const float*)d_in[2];
  const float* bp = (const float*)d_in[3];
  const float* Wc = (const float*)d_in[4];
  const float* bc = (const float*)d_in[5];
  const float* W1 = (const float*)d_in[6];
  const float* b1 = (const float*)d_in[7];
  const float* W2 = (const float*)d_in[8];
  const float* b2 = (const float*)d_in[9];
  float* out = (float*)d_out;

  short* wp_t = (short*)d_ws;
  short* wc_t = wp_t + HDIM * HDIM;
  short* w1_t = wc_t + HDIM * HDIM;
  float* w2v  = (float*)(w1_t + HDIM * 3 * HDIM);
  short* x_bf = (short*)(w2v + HDIM);
  short* Abuf = x_bf + (size_t)N_NODES * HDIM;
  short* Bbuf = Abuf + (size_t)N_NODES * HDIM;

  const size_t needed = (size_t)((char*)(Bbuf + (size_t)N_NODES * HDIM) - (char*)d_ws);

  prep_weights<<<(HDIM * 3 * HDIM + 255) / 256, 256, 0, stream>>>(Wp, Wc, W1, W2,
                                                                  wp_t, wc_t, w1_t, w2v);
  if (ws_size >= needed) {
    node_precompute<<<(N_NODES + BM - 1) / BM, 256, 0, stream>>>(
        x, bp, bc, b1, wp_t, wc_t, w1_t, x_bf, Abuf, Bbuf);
    edge_kernel<<<E_EDGES / BM, 512, 0, stream>>>(ei, x_bf, Abuf, Bbuf, w1_t, w2v, b2, out);
  } else {
    edge_weight_fallback<<<E_EDGES / BM, 512, 0, stream>>>(x, ei, bp, bc, b1, b2,
                                                           wp_t, wc_t, w1_t, w2v, out);
  }
}

// Round 5
// 216.283 us; speedup vs baseline: 1.0725x; 1.0725x over previous
//
#include <hip/hip_runtime.h>
#include <hip/hip_bf16.h>

#define E_EDGES 1000000
#define N_NODES 100000
#define HDIM 128
#define BM 64
#define LDP 136   // padded LDS row stride for bf16 tiles

typedef __attribute__((ext_vector_type(8))) short short8;
typedef __attribute__((ext_vector_type(4))) float f32x4;

// f32 -> bf16 round-to-nearest-even (bit trick, validated)
static __device__ __forceinline__ short f2bf(float f) {
  unsigned int u = __float_as_uint(f);
  unsigned int r = (u + 0x7FFFu + ((u >> 16) & 1u)) >> 16;
  return (short)r;
}
static __device__ __forceinline__ float bf2f(short s) {
  return __uint_as_float(((unsigned int)(unsigned short)s) << 16);
}
// packed f32x2 -> bf16x2 RNE via compiler-visible intrinsic (can emit v_cvt_pk_bf16_f32)
static __device__ __forceinline__ unsigned int pack_bf16_rn(float lo, float hi) {
  __hip_bfloat162 h = __float22bfloat162_rn(make_float2(lo, hi));
  unsigned int u;
  __builtin_memcpy(&u, &h, 4);
  return u;
}

// ---- k0: transpose + bf16-ize weights: Wt[out][in] row-major ----
__global__ void prep_weights(const float* __restrict__ Wp, const float* __restrict__ Wc,
                             const float* __restrict__ W1, const float* __restrict__ W2,
                             short* __restrict__ wp_t, short* __restrict__ wc_t,
                             short* __restrict__ w1_t, float* __restrict__ w2v) {
  int i = blockIdx.x * 256 + threadIdx.x;
  if (i < HDIM * HDIM) {
    int o = i >> 7, k = i & (HDIM - 1);
    wp_t[i] = f2bf(Wp[k * HDIM + o]);
    wc_t[i] = f2bf(Wc[k * HDIM + o]);
  }
  if (i < HDIM * 3 * HDIM) {
    int o = i / (3 * HDIM), k = i - o * (3 * HDIM);
    w1_t[i] = f2bf(W1[k * HDIM + o]);
  }
  if (i < HDIM) w2v[i] = W2[i];
}

// ---- k1: per-node precompute ----
// x_bf[n] = bf16(x[n]);  A[n] = bf16(lrelu(x@Wp+bp)@W1a + b1);  B[n] = bf16(lrelu(x@Wc+bc)@W1b)
__global__ __launch_bounds__(256) void node_precompute(
    const float* __restrict__ x, const float* __restrict__ b_p,
    const float* __restrict__ b_c, const float* __restrict__ b1,
    const short* __restrict__ wp_t, const short* __restrict__ wc_t,
    const short* __restrict__ w1_t,
    short* __restrict__ x_bf, short* __restrict__ Abuf, short* __restrict__ Bbuf) {
  __shared__ __align__(16) short Xt[BM * LDP];
  __shared__ __align__(16) short Yp[BM * LDP];
  __shared__ __align__(16) short Yc[BM * LDP];

  const int t = threadIdx.x;
  const int n0 = blockIdx.x * BM;

  {
    const int lane16 = t & 15, rq = t >> 4, c0 = lane16 * 8;
#pragma unroll
    for (int pass = 0; pass < 4; ++pass) {
      const int row = pass * 16 + rq;
      const int n = n0 + row;
      short8 v;
      if (n < N_NODES) {
        const float* ps = x + (size_t)n * HDIM + c0;
        float4 a = *(const float4*)ps;
        float4 b = *(const float4*)(ps + 4);
        float f[8] = {a.x, a.y, a.z, a.w, b.x, b.y, b.z, b.w};
#pragma unroll
        for (int j = 0; j < 8; ++j) v[j] = f2bf(f[j]);
        *(short8*)&x_bf[(size_t)n * HDIM + c0] = v;
      } else {
#pragma unroll
        for (int j = 0; j < 8; ++j) v[j] = 0;
      }
      *(short8*)&Xt[row * LDP + c0] = v;
    }
  }
  __syncthreads();

  const int l = t & 63;
  const int w = t >> 6;
  const int lr = l & 15;
  const int lg = l >> 4;
  const int aoff = lr * LDP + lg * 8;
  const int na = w * 32 + lr, nb = na + 16;

  const f32x4 zero4 = {0.f, 0.f, 0.f, 0.f};
  f32x4 ap_[4][2], ac_[4][2];
#pragma unroll
  for (int mi = 0; mi < 4; ++mi) {
    ap_[mi][0] = zero4; ap_[mi][1] = zero4;
    ac_[mi][0] = zero4; ac_[mi][1] = zero4;
  }

  const short* wpA = wp_t + na * HDIM + lg * 8;
  const short* wpB = wp_t + nb * HDIM + lg * 8;
  const short* wcA = wc_t + na * HDIM + lg * 8;
  const short* wcB = wc_t + nb * HDIM + lg * 8;

#pragma unroll
  for (int kk = 0; kk < 4; ++kk) {
    short8 b10 = *(const short8*)(wpA + kk * 32);
    short8 b11 = *(const short8*)(wpB + kk * 32);
    short8 b20 = *(const short8*)(wcA + kk * 32);
    short8 b21 = *(const short8*)(wcB + kk * 32);
#pragma unroll
    for (int mi = 0; mi < 4; ++mi) {
      short8 a8 = *(const short8*)&Xt[mi * 16 * LDP + aoff + kk * 32];
      ap_[mi][0] = __builtin_amdgcn_mfma_f32_16x16x32_bf16(a8, b10, ap_[mi][0], 0, 0, 0);
      ap_[mi][1] = __builtin_amdgcn_mfma_f32_16x16x32_bf16(a8, b11, ap_[mi][1], 0, 0, 0);
      ac_[mi][0] = __builtin_amdgcn_mfma_f32_16x16x32_bf16(a8, b20, ac_[mi][0], 0, 0, 0);
      ac_[mi][1] = __builtin_amdgcn_mfma_f32_16x16x32_bf16(a8, b21, ac_[mi][1], 0, 0, 0);
    }
  }

  {
    const float bpa = b_p[na], bpb = b_p[nb];
    const float bca = b_c[na], bcb = b_c[nb];
#pragma unroll
    for (int mi = 0; mi < 4; ++mi) {
#pragma unroll
      for (int r = 0; r < 4; ++r) {
        const int m = mi * 16 + lg * 4 + r;
        float v0 = ap_[mi][0][r] + bpa; v0 = v0 > 0.f ? v0 : 0.01f * v0;
        float v1 = ap_[mi][1][r] + bpb; v1 = v1 > 0.f ? v1 : 0.01f * v1;
        float u0 = ac_[mi][0][r] + bca; u0 = u0 > 0.f ? u0 : 0.01f * u0;
        float u1 = ac_[mi][1][r] + bcb; u1 = u1 > 0.f ? u1 : 0.01f * u1;
        Yp[m * LDP + na] = f2bf(v0);
        Yp[m * LDP + nb] = f2bf(v1);
        Yc[m * LDP + na] = f2bf(u0);
        Yc[m * LDP + nb] = f2bf(u1);
      }
    }
  }
  __syncthreads();

  f32x4 aa_[4][2], ab_[4][2];
#pragma unroll
  for (int mi = 0; mi < 4; ++mi) {
    aa_[mi][0] = zero4; aa_[mi][1] = zero4;
    ab_[mi][0] = zero4; ab_[mi][1] = zero4;
  }
  const short* w1Aa = w1_t + na * (3 * HDIM) + lg * 8;
  const short* w1Ab = w1_t + nb * (3 * HDIM) + lg * 8;
#pragma unroll
  for (int kk = 0; kk < 4; ++kk) {
    short8 ba0 = *(const short8*)(w1Aa + kk * 32);
    short8 ba1 = *(const short8*)(w1Ab + kk * 32);
    short8 bb0 = *(const short8*)(w1Aa + HDIM + kk * 32);
    short8 bb1 = *(const short8*)(w1Ab + HDIM + kk * 32);
#pragma unroll
    for (int mi = 0; mi < 4; ++mi) {
      short8 ayp = *(const short8*)&Yp[mi * 16 * LDP + aoff + kk * 32];
      short8 ayc = *(const short8*)&Yc[mi * 16 * LDP + aoff + kk * 32];
      aa_[mi][0] = __builtin_amdgcn_mfma_f32_16x16x32_bf16(ayp, ba0, aa_[mi][0], 0, 0, 0);
      aa_[mi][1] = __builtin_amdgcn_mfma_f32_16x16x32_bf16(ayp, ba1, aa_[mi][1], 0, 0, 0);
      ab_[mi][0] = __builtin_amdgcn_mfma_f32_16x16x32_bf16(ayc, bb0, ab_[mi][0], 0, 0, 0);
      ab_[mi][1] = __builtin_amdgcn_mfma_f32_16x16x32_bf16(ayc, bb1, ab_[mi][1], 0, 0, 0);
    }
  }

  {
    const float b1a = b1[na], b1b = b1[nb];
#pragma unroll
    for (int mi = 0; mi < 4; ++mi) {
#pragma unroll
      for (int r = 0; r < 4; ++r) {
        const int m = mi * 16 + lg * 4 + r;
        const int n = n0 + m;
        if (n < N_NODES) {
          Abuf[(size_t)n * HDIM + na] = f2bf(aa_[mi][0][r] + b1a);
          Abuf[(size_t)n * HDIM + nb] = f2bf(aa_[mi][1][r] + b1b);
          Bbuf[(size_t)n * HDIM + na] = f2bf(ab_[mi][0][r]);
          Bbuf[(size_t)n * HDIM + nb] = f2bf(ab_[mi][1][r]);
        }
      }
    }
  }
}

// ---- k2: per-edge: h = relu(S + |x_s-x_d|@W1c); out = sigmoid(h.w2 + b2) ----
// S = A[s] + B[d] staged vectorized into bf16 LDS (small LDS -> 4 blocks/CU).
__global__ __launch_bounds__(512, 8) void edge_kernel(
    const int* __restrict__ ei, const short* __restrict__ x_bf,
    const short* __restrict__ Abuf, const short* __restrict__ Bbuf,
    const short* __restrict__ w1_t, const float* __restrict__ w2v,
    const float* __restrict__ b2, float* __restrict__ out) {
  __shared__ __align__(16) short Dt[BM * LDP];   // 17408 B
  __shared__ __align__(16) short St[BM * LDP];   // 17408 B (bf16 S)
  __shared__ float partial[8][BM];               // 2048 B

  const int t = threadIdx.x;
  const int e0 = blockIdx.x * BM;

  {
    const int lane16 = t & 15, rq = t >> 4, c0 = lane16 * 8;
#pragma unroll
    for (int pass = 0; pass < 2; ++pass) {
      const int row = pass * 32 + rq;
      const int s = ei[e0 + row];
      const int d = ei[E_EDGES + e0 + row];
      short8 p8 = *(const short8*)(x_bf + (size_t)s * HDIM + c0);
      short8 c8 = *(const short8*)(x_bf + (size_t)d * HDIM + c0);
      short8 a8 = *(const short8*)(Abuf + (size_t)s * HDIM + c0);
      short8 b8 = *(const short8*)(Bbuf + (size_t)d * HDIM + c0);
      float df[8], sf[8];
#pragma unroll
      for (int j = 0; j < 8; ++j) {
        df[j] = fabsf(bf2f(p8[j]) - bf2f(c8[j]));
        sf[j] = bf2f(a8[j]) + bf2f(b8[j]);
      }
      uint4 vd, vs;
      vd.x = pack_bf16_rn(df[0], df[1]);
      vd.y = pack_bf16_rn(df[2], df[3]);
      vd.z = pack_bf16_rn(df[4], df[5]);
      vd.w = pack_bf16_rn(df[6], df[7]);
      vs.x = pack_bf16_rn(sf[0], sf[1]);
      vs.y = pack_bf16_rn(sf[2], sf[3]);
      vs.z = pack_bf16_rn(sf[4], sf[5]);
      vs.w = pack_bf16_rn(sf[6], sf[7]);
      *(uint4*)&Dt[row * LDP + c0] = vd;
      *(uint4*)&St[row * LDP + c0] = vs;
    }
  }
  __syncthreads();

  const int l = t & 63;
  const int w = t >> 6;   // 0..7
  const int lr = l & 15;
  const int lg = l >> 4;
  const int na = w * 16 + lr;
  const int aoff = lr * LDP + lg * 8;

  // acc init = S (bf16 from LDS)
  f32x4 acc[4];
#pragma unroll
  for (int mi = 0; mi < 4; ++mi) {
#pragma unroll
    for (int r = 0; r < 4; ++r) {
      acc[mi][r] = bf2f(St[(mi * 16 + lg * 4 + r) * LDP + na]);
    }
  }

  // GEMM: D @ W1c (K=128)
  const short* w1D = w1_t + na * (3 * HDIM) + 2 * HDIM + lg * 8;
#pragma unroll
  for (int kk = 0; kk < 4; ++kk) {
    short8 b8 = *(const short8*)(w1D + kk * 32);
#pragma unroll
    for (int mi = 0; mi < 4; ++mi) {
      short8 a8 = *(const short8*)&Dt[mi * 16 * LDP + aoff + kk * 32];
      acc[mi] = __builtin_amdgcn_mfma_f32_16x16x32_bf16(a8, b8, acc[mi], 0, 0, 0);
    }
  }

  // epilogue: relu, dot w2, 16-lane reduce
  {
    const float w2a = w2v[na];
#pragma unroll
    for (int mi = 0; mi < 4; ++mi) {
#pragma unroll
      for (int r = 0; r < 4; ++r) {
        float h = acc[mi][r] > 0.f ? acc[mi][r] : 0.f;
        float v = h * w2a;
        v += __shfl_xor(v, 1);
        v += __shfl_xor(v, 2);
        v += __shfl_xor(v, 4);
        v += __shfl_xor(v, 8);
        if (lr == 0) partial[w][mi * 16 + lg * 4 + r] = v;
      }
    }
  }
  __syncthreads();

  if (t < BM) {
    float z = partial[0][t] + partial[1][t] + partial[2][t] + partial[3][t] +
              partial[4][t] + partial[5][t] + partial[6][t] + partial[7][t] + b2[0];
    out[e0 + t] = 1.0f / (1.0f + __expf(-z));
  }
}

// ---- fallback (validated v2 path) if workspace is too small ----
__global__ __launch_bounds__(512, 4) void edge_weight_fallback(
    const float* __restrict__ x, const int* __restrict__ ei,
    const float* __restrict__ b_p, const float* __restrict__ b_c,
    const float* __restrict__ b1, const float* __restrict__ b2,
    const short* __restrict__ wp_t, const short* __restrict__ wc_t,
    const short* __restrict__ w1_t, const float* __restrict__ w2v,
    float* __restrict__ out) {
  __shared__ __align__(16) short Pt[BM * LDP];
  __shared__ __align__(16) short Ct[BM * LDP];
  __shared__ __align__(16) short Dt[BM * LDP];
  __shared__ float partial[8][BM];

  const int t = threadIdx.x;
  const int e0 = blockIdx.x * BM;
  {
    const int lane16 = t & 15, rq = t >> 4, c0 = lane16 * 8;
#pragma unroll
    for (int pass = 0; pass < 2; ++pass) {
      const int row = pass * 32 + rq;
      const int ip = ei[e0 + row];
      const int ic = ei[E_EDGES + e0 + row];
      const float* ps = x + (size_t)ip * HDIM + c0;
      const float* cs = x + (size_t)ic * HDIM + c0;
      float4 pa = *(const float4*)ps, pb = *(const float4*)(ps + 4);
      float4 ca = *(const float4*)cs, cb = *(const float4*)(cs + 4);
      float pf[8] = {pa.x, pa.y, pa.z, pa.w, pb.x, pb.y, pb.z, pb.w};
      float cf[8] = {ca.x, ca.y, ca.z, ca.w, cb.x, cb.y, cb.z, cb.w};
      short8 vp, vc, vd;
#pragma unroll
      for (int j = 0; j < 8; ++j) {
        vp[j] = f2bf(pf[j]); vc[j] = f2bf(cf[j]); vd[j] = f2bf(fabsf(pf[j] - cf[j]));
      }
      *(short8*)&Pt[row * LDP + c0] = vp;
      *(short8*)&Ct[row * LDP + c0] = vc;
      *(short8*)&Dt[row * LDP + c0] = vd;
    }
  }
  __syncthreads();
  const int l = t & 63, w = t >> 6, lr = l & 15, lg = l >> 4;
  const int n0 = w * 16, na = n0 + lr, aoff = lr * LDP + lg * 8;
  const f32x4 zero4 = {0.f, 0.f, 0.f, 0.f};
  f32x4 acc1[4], acc2[4], acc3[4];
#pragma unroll
  for (int mi = 0; mi < 4; ++mi) { acc1[mi] = zero4; acc2[mi] = zero4; acc3[mi] = zero4; }
  const short* wpA = wp_t + na * HDIM + lg * 8;
  const short* wcA = wc_t + na * HDIM + lg * 8;
  const short* w1A = w1_t + na * (3 * HDIM) + lg * 8;
#pragma unroll
  for (int kk = 0; kk < 4; ++kk) {
    short8 bp8 = *(const short8*)(wpA + kk * 32);
    short8 bc8 = *(const short8*)(wcA + kk * 32);
    short8 bd8 = *(const short8*)(w1A + 2 * HDIM + kk * 32);
#pragma unroll
    for (int mi = 0; mi < 4; ++mi) {
      short8 ap = *(const short8*)&Pt[mi * 16 * LDP + aoff + kk * 32];
      short8 ac = *(const short8*)&Ct[mi * 16 * LDP + aoff + kk * 32];
      short8 ad = *(const short8*)&Dt[mi * 16 * LDP + aoff + kk * 32];
      acc1[mi] = __builtin_amdgcn_mfma_f32_16x16x32_bf16(ap, bp8, acc1[mi], 0, 0, 0);
      acc2[mi] = __builtin_amdgcn_mfma_f32_16x16x32_bf16(ac, bc8, acc2[mi], 0, 0, 0);
      acc3[mi] = __builtin_amdgcn_mfma_f32_16x16x32_bf16(ad, bd8, acc3[mi], 0, 0, 0);
    }
  }
  __syncthreads();
  {
    const float bpa = b_p[na], bca = b_c[na];
#pragma unroll
    for (int mi = 0; mi < 4; ++mi) {
#pragma unroll
      for (int r = 0; r < 4; ++r) {
        const int m = mi * 16 + lg * 4 + r;
        float v0 = acc1[mi][r] + bpa; v0 = v0 > 0.f ? v0 : 0.01f * v0;
        float u0 = acc2[mi][r] + bca; u0 = u0 > 0.f ? u0 : 0.01f * u0;
        Pt[m * LDP + na] = f2bf(v0);
        Ct[m * LDP + na] = f2bf(u0);
      }
    }
  }
  __syncthreads();
#pragma unroll
  for (int kk = 0; kk < 4; ++kk) {
    short8 b0 = *(const short8*)(w1A + kk * 32);
    short8 b1f = *(const short8*)(w1A + HDIM + kk * 32);
#pragma unroll
    for (int mi = 0; mi < 4; ++mi) {
      short8 a0 = *(const short8*)&Pt[mi * 16 * LDP + aoff + kk * 32];
      short8 a1 = *(const short8*)&Ct[mi * 16 * LDP + aoff + kk * 32];
      acc3[mi] = __builtin_amdgcn_mfma_f32_16x16x32_bf16(a0, b0, acc3[mi], 0, 0, 0);
      acc3[mi] = __builtin_amdgcn_mfma_f32_16x16x32_bf16(a1, b1f, acc3[mi], 0, 0, 0);
    }
  }
  {
    const float b1a = b1[na], w2a = w2v[na];
#pragma unroll
    for (int mi = 0; mi < 4; ++mi) {
#pragma unroll
      for (int r = 0; r < 4; ++r) {
        float h0 = acc3[mi][r] + b1a; h0 = h0 > 0.f ? h0 : 0.f;
        float v = h0 * w2a;
        v += __shfl_xor(v, 1); v += __shfl_xor(v, 2);
        v += __shfl_xor(v, 4); v += __shfl_xor(v, 8);
        if (lr == 0) partial[w][mi * 16 + lg * 4 + r] = v;
      }
    }
  }
  __syncthreads();
  if (t < BM) {
    float z = partial[0][t] + partial[1][t] + partial[2][t] + partial[3][t] +
              partial[4][t] + partial[5][t] + partial[6][t] + partial[7][t] + b2[0];
    out[e0 + t] = 1.0f / (1.0f + __expf(-z));
  }
}

extern "C" void kernel_launch(void* const* d_in, const int* in_sizes, int n_in,
                              void* d_out, int out_size, void* d_ws, size_t ws_size,
                              hipStream_t stream) {
  const float* x  = (const float*)d_in[0];
  const int*   ei = (const int*)d_in[1];
  const float* Wp = (const float*)d_in[2];
  const float* bp = (const float*)d_in[3];
  const float* Wc = (const float*)d_in[4];
  const float* bc = (const float*)d_in[5];
  const float* W1 = (const float*)d_in[6];
  const float* b1 = (const float*)d_in[7];
  const float* W2 = (const float*)d_in[8];
  const float* b2 = (const float*)d_in[9];
  float* out = (float*)d_out;

  short* wp_t = (short*)d_ws;
  short* wc_t = wp_t + HDIM * HDIM;
  short* w1_t = wc_t + HDIM * HDIM;
  float* w2v  = (float*)(w1_t + HDIM * 3 * HDIM);
  short* x_bf = (short*)(w2v + HDIM);
  short* Abuf = x_bf + (size_t)N_NODES * HDIM;
  short* Bbuf = Abuf + (size_t)N_NODES * HDIM;

  const size_t needed = (size_t)((char*)(Bbuf + (size_t)N_NODES * HDIM) - (char*)d_ws);

  prep_weights<<<(HDIM * 3 * HDIM + 255) / 256, 256, 0, stream>>>(Wp, Wc, W1, W2,
                                                                  wp_t, wc_t, w1_t, w2v);
  if (ws_size >= needed) {
    node_precompute<<<(N_NODES + BM - 1) / BM, 256, 0, stream>>>(
        x, bp, bc, b1, wp_t, wc_t, w1_t, x_bf, Abuf, Bbuf);
    edge_kernel<<<E_EDGES / BM, 512, 0, stream>>>(ei, x_bf, Abuf, Bbuf, w1_t, w2v, b2, out);
  } else {
    edge_weight_fallback<<<E_EDGES / BM, 512, 0, stream>>>(x, ei, bp, bc, b1, b2,
                                                           wp_t, wc_t, w1_t, w2v, out);
  }
}